// Round 15
// baseline (199.338 us; speedup 1.0000x reference)
//
#include <hip/hip_runtime.h>

#define NN 2048
#define PITCH 72   // u16 elems per LDS row (K tiles): 144B -> 16B-aligned rows
#define MPITCH 264 // u16 elems per LDS row (mix): 528B

typedef __attribute__((ext_vector_type(8))) _Float16 half8;  // 8 fp16 = 4 VGPRs (MFMA A/B frag)
typedef __attribute__((ext_vector_type(4))) float floatx4;   // MFMA C/D frag

static_assert(sizeof(half8) == 16, "");

#define MRINIT -3.0e38f

__device__ __forceinline__ unsigned short f2h(float f) {
    union { _Float16 h; unsigned short u; } v;
    v.h = (_Float16)f;  // RNE
    return v.u;
}
__device__ __forceinline__ float h2f(unsigned short u) {
    union { unsigned short u; _Float16 h; } v;
    v.u = u;
    return (float)v.h;
}
__device__ __forceinline__ unsigned int pk2h(float a, float b) {  // v_cvt_pkrtz_f16_f32
    union { __fp16 __attribute__((ext_vector_type(2))) h; unsigned int u; } v;
    v.h = __builtin_amdgcn_cvt_pkrtz(a, b);
    return v.u;
}
// barrier that does NOT drain vmcnt: LDS-visibility only; prefetch loads stay in flight.
__device__ __forceinline__ void barrier_lds_only() {
    __asm__ __volatile__("" ::: "memory");
    __builtin_amdgcn_s_waitcnt(0xC07F);  // vmcnt=63, expcnt=7, lgkmcnt=0
    __builtin_amdgcn_s_barrier();
    __asm__ __volatile__("" ::: "memory");
}

// ---------- mask = (graph + I) > 0, packed bits, TRANSPOSED: mbitsT[w*2048 + i] ----------
// w = column-word 0..63 (32 cols each); lanes reading consecutive rows i are coalesced.
__global__ __launch_bounds__(256) void mask_kernel(const int* __restrict__ graph,
                                                   unsigned int* __restrict__ mbitsT) {
    const int t = threadIdx.x;
    const int lane = t & 63;
    const int W = (blockIdx.x << 2) + (t >> 6);
    const int i = W >> 5;
    const int cb = W & 31;
    const int j = (cb << 6) + lane;
    const int g = graph[(size_t)i * NN + j];
    const unsigned long long bal = __ballot((g > 0) || (i == j));
    if (lane == 0)  mbitsT[((cb << 1) << 11) + i]     = (unsigned int)bal;
    if (lane == 32) mbitsT[(((cb << 1) + 1) << 11) + i] = (unsigned int)(bal >> 32);
}

// ---------- proj as MFMA GEMM: h[b,h,n,d] = sum_c x[b,n,c] * Wh[h,d,c] ----------
__global__ __launch_bounds__(256) void proj_gemm(const float* __restrict__ x,
                                                 const float* __restrict__ Wh,
                                                 unsigned short* __restrict__ hout) {
    __shared__ unsigned short xs[64 * PITCH];
    __shared__ unsigned short wh[4 * 64 * PITCH];
    const int t = threadIdx.x;
    const int b = blockIdx.x >> 5;
    const int n0 = (blockIdx.x & 31) << 6;
    for (int i = t; i < 512; i += 256) {
        const int r = i >> 3, c8 = (i & 7) << 3;
        const float* xp = x + (((size_t)b * NN + n0 + r) << 6) + c8;
        const float4 f0 = *(const float4*)(xp);
        const float4 f1 = *(const float4*)(xp + 4);
        uint4 pk;
        pk.x = pk2h(f0.x, f0.y); pk.y = pk2h(f0.z, f0.w);
        pk.z = pk2h(f1.x, f1.y); pk.w = pk2h(f1.z, f1.w);
        *(uint4*)(&xs[r * PITCH + c8]) = pk;
    }
    for (int i = t; i < 2048; i += 256) {
        const int hd = i >> 3, c8 = (i & 7) << 3;
        const float* wp = Wh + ((size_t)hd << 6) + c8;
        const float4 f0 = *(const float4*)(wp);
        const float4 f1 = *(const float4*)(wp + 4);
        uint4 pk;
        pk.x = pk2h(f0.x, f0.y); pk.y = pk2h(f0.z, f0.w);
        pk.z = pk2h(f1.x, f1.y); pk.w = pk2h(f1.z, f1.w);
        *(uint4*)(&wh[hd * PITCH + c8]) = pk;
    }
    __syncthreads();
    const int wave = t >> 6;  // head
    const int m = t & 15;
    const int quad = (t >> 4) & 3;
    half8 bf0[4], bf1[4];
#pragma unroll
    for (int nt = 0; nt < 4; ++nt) {
        const int row = (wave << 6) + (nt << 4) + m;
        bf0[nt] = *(const half8*)(&wh[row * PITCH + (quad << 3)]);
        bf1[nt] = *(const half8*)(&wh[row * PITCH + 32 + (quad << 3)]);
    }
    floatx4 acc[4][4];
#pragma unroll
    for (int mt = 0; mt < 4; ++mt)
#pragma unroll
        for (int nt = 0; nt < 4; ++nt) acc[mt][nt] = floatx4{0.f, 0.f, 0.f, 0.f};
#pragma unroll
    for (int mt = 0; mt < 4; ++mt) {
        const half8 a0 = *(const half8*)(&xs[((mt << 4) + m) * PITCH + (quad << 3)]);
        const half8 a1 = *(const half8*)(&xs[((mt << 4) + m) * PITCH + 32 + (quad << 3)]);
#pragma unroll
        for (int nt = 0; nt < 4; ++nt) {
            acc[mt][nt] = __builtin_amdgcn_mfma_f32_16x16x32_f16(a0, bf0[nt], acc[mt][nt], 0, 0, 0);
            acc[mt][nt] = __builtin_amdgcn_mfma_f32_16x16x32_f16(a1, bf1[nt], acc[mt][nt], 0, 0, 0);
        }
    }
    unsigned short* hp = hout + ((((size_t)(b << 2) + wave) * NN + n0) << 6) + m;
#pragma unroll
    for (int mt = 0; mt < 4; ++mt)
#pragma unroll
        for (int reg = 0; reg < 4; ++reg)
#pragma unroll
            for (int nt = 0; nt < 4; ++nt)
                hp[(((mt << 4) + (quad << 2) + reg) << 6) + (nt << 4)] = f2h(acc[mt][nt][reg]);
}

// ---------- fused GAT layer (rotation swizzles, O^T accumulation, early mask loads) ----------
template <int QG, int OUTMODE, int NSPLIT>
__global__ __launch_bounds__(256) void gat_flash(const unsigned short* __restrict__ Hm,
                                                 const unsigned int* __restrict__ mbitsT,
                                                 const float* __restrict__ bias,
                                                 const int bias_mod,
                                                 void* __restrict__ OutP,
                                                 float2* __restrict__ mlP) {
    __shared__ unsigned short Ks[2][64 * PITCH];
    __shared__ unsigned short Kts[2][64 * PITCH];
    __shared__ unsigned short Ps[4 * QG * 16 * 64];

    const int t = threadIdx.x;
    const int wave = t >> 6;
    const int lane = t & 63;
    const int quad = lane >> 4;
    const int m = lane & 15;

    const int qtbits = 4;  // QG==2: 128 q-rows/block
    const int sbits = (NSPLIT == 4) ? 2 : (NSPLIT == 2) ? 1 : 0;
    const int bid = blockIdx.x;
    const int qt = bid & ((1 << qtbits) - 1);
    const int split = (bid >> qtbits) & (NSPLIT - 1);
    const int mat = bid >> (qtbits + sbits);
    const int q0 = qt << 7;
    const int nkt = 32 / NSPLIT;
    const int kt0 = split * nkt;

    const unsigned short* Hb = Hm + ((size_t)mat << 17);
    const int wbase = q0 + wave * (16 * QG);

    const _Float16 LOG2E = (_Float16)1.44269504f;
    half8 bq0[QG], bq1[QG];
    int gq[QG];
#pragma unroll
    for (int g = 0; g < QG; ++g) {
        gq[g] = wbase + (g << 4) + m;
        bq0[g] = *(const half8*)(Hb + (gq[g] << 6) + (quad << 3)) * LOG2E;
        bq1[g] = *(const half8*)(Hb + (gq[g] << 6) + 32 + (quad << 3)) * LOG2E;
    }

    const int p = t >> 3;
    const int cc = t & 7;
    const int jch = p >> 2;
    const int jo = (p & 3) << 1;

    float mr[QG], lr[QG];
    floatx4 O[QG][4];
#pragma unroll
    for (int g = 0; g < QG; ++g) {
        mr[g] = MRINIT;
        lr[g] = 0.f;
#pragma unroll
        for (int nt = 0; nt < 4; ++nt) O[g][nt] = floatx4{0.f, 0.f, 0.f, 0.f};
    }

    const int msw = m & 7;
    int psb[QG];
#pragma unroll
    for (int g = 0; g < QG; ++g) psb[g] = (wave * QG + g) * 1024 + (m << 6);

    const unsigned short* kg0 = Hb + (((kt0 << 6) + (p << 1)) << 6) + (cc << 3);
    half8 ra = *(const half8*)(kg0);
    half8 rb = *(const half8*)(kg0 + 64);

    for (int it = 0; it < nkt; ++it) {
        const int kt = kt0 + it;
        unsigned short* KS = Ks[it & 1];
        unsigned short* KT = Kts[it & 1];
        // ---- early coalesced mask loads (no LDS dep; latency hidden behind QK MFMAs) ----
        unsigned int w0[QG], w1[QG];
#pragma unroll
        for (int g = 0; g < QG; ++g) {
            w0[g] = mbitsT[((kt << 1) << 11) + gq[g]];
            w1[g] = mbitsT[(((kt << 1) + 1) << 11) + gq[g]];
        }
        // ---- write prefetched staging tile kt (VGPR->LDS) ----
        *(half8*)(&KS[(p << 1) * PITCH + (cc << 3)]) = ra;
        *(half8*)(&KS[((p << 1) + 1) * PITCH + (cc << 3)]) = rb;
        union { half8 v; unsigned int u[4]; } kaU, kbU;
        kaU.v = ra;
        kbU.v = rb;
#pragma unroll
        for (int c = 0; c < 4; ++c) {
            const unsigned int ua = kaU.u[c];
            const unsigned int ub = kbU.u[c];
            const unsigned int lo = __builtin_amdgcn_perm(ub, ua, 0x05040100);
            const unsigned int hi = __builtin_amdgcn_perm(ub, ua, 0x07060302);
            const int d0 = (cc << 3) + (c << 1);
            const int pos = (((jch + cc) & 7) << 3) + jo;  // rotation swizzle
            *(unsigned int*)(&KT[d0 * PITCH + pos]) = lo;
            *(unsigned int*)(&KT[(d0 + 1) * PITCH + pos]) = hi;
        }
        const int ktn = kt0 + ((it + 1) & (nkt - 1));
        const unsigned short* kgn = Hb + (((ktn << 6) + (p << 1)) << 6) + (cc << 3);
        ra = *(const half8*)(kgn);
        rb = *(const half8*)(kgn + 64);

        barrier_lds_only();

        // ---- S^T = K * Q^T : A = K rows from LDS, shared across groups ----
        floatx4 a[QG][4];
#pragma unroll
        for (int jt = 0; jt < 4; ++jt) {
            const half8 k0 = *(const half8*)(&KS[((jt << 4) + m) * PITCH + (quad << 3)]);
            const half8 k1 = *(const half8*)(&KS[((jt << 4) + m) * PITCH + 32 + (quad << 3)]);
#pragma unroll
            for (int g = 0; g < QG; ++g) {
                floatx4 z = {0.f, 0.f, 0.f, 0.f};
                z = __builtin_amdgcn_mfma_f32_16x16x32_f16(k0, bq0[g], z, 0, 0, 0);
                z = __builtin_amdgcn_mfma_f32_16x16x32_f16(k1, bq1[g], z, 0, 0, 0);
                a[g][jt] = z;
            }
        }

        // ---- per group: mask, online softmax (tree max), Ps write, O rescale ----
#pragma unroll
        for (int g = 0; g < QG; ++g) {
            float vmax[4];
#pragma unroll
            for (int jt = 0; jt < 4; ++jt) {
                const unsigned int wv = (jt < 2) ? w0[g] : w1[g];
                const unsigned int bits = (wv >> (((jt & 1) << 4) + (quad << 2))) & 0xFu;
                float v0 = ((bits >> 0) & 1u) ? a[g][jt][0] : MRINIT;
                float v1 = ((bits >> 1) & 1u) ? a[g][jt][1] : MRINIT;
                float v2 = ((bits >> 2) & 1u) ? a[g][jt][2] : MRINIT;
                float v3 = ((bits >> 3) & 1u) ? a[g][jt][3] : MRINIT;
                a[g][jt][0] = v0; a[g][jt][1] = v1; a[g][jt][2] = v2; a[g][jt][3] = v3;
                vmax[jt] = fmaxf(fmaxf(v0, v1), fmaxf(v2, v3));  // tree, not chain
            }
            float tmx = fmaxf(fmaxf(vmax[0], vmax[1]), fmaxf(vmax[2], vmax[3]));
            tmx = fmaxf(tmx, __shfl_xor(tmx, 16));
            tmx = fmaxf(tmx, __shfl_xor(tmx, 32));
            const float mnew = fmaxf(mr[g], tmx);
            const float alpha = __builtin_amdgcn_exp2f(mr[g] - mnew);
            const bool need = __any(mnew > mr[g]);

            float psum = 0.f;
#pragma unroll
            for (int jt = 0; jt < 4; ++jt) {
                const float p0 = __builtin_amdgcn_exp2f(a[g][jt][0] - mnew);
                const float p1 = __builtin_amdgcn_exp2f(a[g][jt][1] - mnew);
                const float p2 = __builtin_amdgcn_exp2f(a[g][jt][2] - mnew);
                const float p3 = __builtin_amdgcn_exp2f(a[g][jt][3] - mnew);
                psum += (p0 + p1) + (p2 + p3);
                const int ch = (jt << 1) + (quad >> 1);
                *(uint2*)(&Ps[psb[g] + (((ch + msw) & 7) << 3) + ((quad & 1) << 2)]) =
                    make_uint2(pk2h(p0, p1), pk2h(p2, p3));
            }
            psum += __shfl_xor(psum, 16);
            psum += __shfl_xor(psum, 32);
            lr[g] = lr[g] * alpha + psum;
            mr[g] = mnew;

            if (need) {
#pragma unroll
                for (int nt = 0; nt < 4; ++nt) {
                    O[g][nt][0] *= alpha;  // O^T: lane's column = its own q-row
                    O[g][nt][1] *= alpha;
                    O[g][nt][2] *= alpha;
                    O[g][nt][3] *= alpha;
                }
            }
        }

        __builtin_amdgcn_wave_barrier();
        __asm__ __volatile__("" ::: "memory");

        // ---- O^T += V^T * P^T : A = KT rows, B = Ps rows ----
        half8 pa0[QG], pa1[QG];
#pragma unroll
        for (int g = 0; g < QG; ++g) {
            pa0[g] = *(const half8*)(&Ps[psb[g] + (((quad + msw) & 7) << 3)]);
            pa1[g] = *(const half8*)(&Ps[psb[g] + (((4 + quad + msw) & 7) << 3)]);
        }
#pragma unroll
        for (int nt = 0; nt < 4; ++nt) {
            const int d = (nt << 4) + m;
            const int sw = (d >> 3) & 7;
            const half8 v0 = *(const half8*)(&KT[d * PITCH + (((quad + sw) & 7) << 3)]);
            const half8 v1 = *(const half8*)(&KT[d * PITCH + (((4 + quad + sw) & 7) << 3)]);
#pragma unroll
            for (int g = 0; g < QG; ++g) {
                O[g][nt] = __builtin_amdgcn_mfma_f32_16x16x32_f16(v0, pa0[g], O[g][nt], 0, 0, 0);
                O[g][nt] = __builtin_amdgcn_mfma_f32_16x16x32_f16(v1, pa1[g], O[g][nt], 0, 0, 0);
            }
        }
    }

    // ---- epilogue (O^T: lane holds q-row gq[g], d = 16nt + 4quad + reg) ----
    if (OUTMODE == 2) {
        unsigned short* Op = (unsigned short*)OutP;
        const size_t pbase = ((size_t)(split << 3) + mat) * NN;
#pragma unroll
        for (int g = 0; g < QG; ++g) {
            unsigned short* Ob = Op + ((pbase + gq[g]) << 6) + (quad << 2);
#pragma unroll
            for (int nt = 0; nt < 4; ++nt)
                *(uint2*)(Ob + (nt << 4)) = make_uint2(pk2h(O[g][nt][0], O[g][nt][1]),
                                                       pk2h(O[g][nt][2], O[g][nt][3]));
        }
        if (lane < 16) {
#pragma unroll
            for (int g = 0; g < QG; ++g)
                mlP[pbase + wbase + (g << 4) + m] = make_float2(mr[g], lr[g]);
        }
        return;
    }

    // OUTMODE 0: normalize, +bias, leaky, fp16 store
    const int boff = (mat % bias_mod) << 6;
    float4 bb[4];
#pragma unroll
    for (int nt = 0; nt < 4; ++nt)
        bb[nt] = *(const float4*)(bias + boff + (nt << 4) + (quad << 2));
#pragma unroll
    for (int g = 0; g < QG; ++g) {
        const float li = 1.f / lr[g];
        unsigned short* op = (unsigned short*)OutP + (((size_t)mat * NN + gq[g]) << 6) + (quad << 2);
#pragma unroll
        for (int nt = 0; nt < 4; ++nt) {
            float z0 = O[g][nt][0] * li + bb[nt].x;
            float z1 = O[g][nt][1] * li + bb[nt].y;
            float z2 = O[g][nt][2] * li + bb[nt].z;
            float z3 = O[g][nt][3] * li + bb[nt].w;
            z0 = (z0 > 0.f) ? z0 : 0.2f * z0;
            z1 = (z1 > 0.f) ? z1 : 0.2f * z1;
            z2 = (z2 > 0.f) ? z2 : 0.2f * z2;
            z3 = (z3 > 0.f) ? z3 : 0.2f * z3;
            *(uint2*)(op + (nt << 4)) = make_uint2(pk2h(z0, z1), pk2h(z2, z3));
        }
    }
}

// ---------- mix as MFMA GEMM: h2[b,r,d] = sum_k z[b,r,k] * Wo[d,k] ----------
__global__ __launch_bounds__(256) void mix_gemm(const unsigned short* __restrict__ oh,
                                                const float* __restrict__ Wo,
                                                unsigned short* __restrict__ h2) {
    __shared__ unsigned short zs[64 * MPITCH];
    __shared__ unsigned short wsm[64 * MPITCH];
    const int t = threadIdx.x;
    const int b = blockIdx.x >> 5;
    const int n0 = (blockIdx.x & 31) << 6;
    for (int i = t; i < 2048; i += 256) {
        const int hh = i >> 9;
        const int r = (i >> 3) & 63;
        const int d8 = i & 7;
        const half8 v = *(const half8*)(oh + ((((size_t)b << 2) + hh) * NN + n0 + r) * 64 + (d8 << 3));
        *(half8*)(&zs[r * MPITCH + (hh << 6) + (d8 << 3)]) = v;
    }
    for (int i = t; i < 2048; i += 256) {
        const int d = i >> 5;
        const int k0 = (i & 31) << 3;
        const float4 f0 = *(const float4*)(Wo + (d << 8) + k0);
        const float4 f1 = *(const float4*)(Wo + (d << 8) + k0 + 4);
        uint4 pk;
        pk.x = pk2h(f0.x, f0.y);
        pk.y = pk2h(f0.z, f0.w);
        pk.z = pk2h(f1.x, f1.y);
        pk.w = pk2h(f1.z, f1.w);
        *(uint4*)(&wsm[d * MPITCH + k0]) = pk;
    }
    __syncthreads();
    const int wave = t >> 6;
    const int m = t & 15;
    const int quad = (t >> 4) & 3;
    const int ar = (wave << 4) + m;
    floatx4 acc[4] = {{0.f, 0.f, 0.f, 0.f}, {0.f, 0.f, 0.f, 0.f},
                      {0.f, 0.f, 0.f, 0.f}, {0.f, 0.f, 0.f, 0.f}};
#pragma unroll
    for (int chunk = 0; chunk < 8; ++chunk) {
        const int k0 = chunk << 5;
        const half8 af = *(const half8*)(&zs[ar * MPITCH + k0 + (quad << 3)]);
#pragma unroll
        for (int nt = 0; nt < 4; ++nt) {
            const half8 bf = *(const half8*)(&wsm[((nt << 4) + m) * MPITCH + k0 + (quad << 3)]);
            acc[nt] = __builtin_amdgcn_mfma_f32_16x16x32_f16(af, bf, acc[nt], 0, 0, 0);
        }
    }
    unsigned short* hp = h2 + (((size_t)b * NN + n0 + (wave << 4) + (quad << 2)) << 6) + m;
#pragma unroll
    for (int reg = 0; reg < 4; ++reg)
#pragma unroll
        for (int nt = 0; nt < 4; ++nt)
            hp[(reg << 6) + (nt << 4)] = f2h(acc[nt][reg]);
}

// ---------- combine 4 split-K partials + bias + leaky + LayerNorm (fp32 out) ----------
__global__ __launch_bounds__(256) void combine_ln(const unsigned short* __restrict__ Opart,
                                                  const float2* __restrict__ ml,
                                                  const float* __restrict__ bo,
                                                  const float* __restrict__ gamma,
                                                  const float* __restrict__ beta,
                                                  float* __restrict__ out) {
    const int t = threadIdx.x;
    const int lane = t & 63;
    const size_t r0 = (size_t)((blockIdx.x << 2) + (t >> 6));  // mat*2048 + row
    float2 sv[4];
    float mm = MRINIT;
#pragma unroll
    for (int s = 0; s < 4; ++s) {
        sv[s] = ml[(size_t)(NN * 8) * s + r0];
        mm = fmaxf(mm, sv[s].x);
    }
    float l = 0.f, osum = 0.f;
#pragma unroll
    for (int s = 0; s < 4; ++s) {
        const float c = __builtin_amdgcn_exp2f(sv[s].x - mm);
        l += sv[s].y * c;
        osum += h2f(Opart[(((size_t)(NN * 8) * s + r0) << 6) + lane]) * c;
    }
    float v = osum / l + bo[lane];
    v = (v > 0.f) ? v : 0.2f * v;
    float s = v;
    float sq = v * v;
#pragma unroll
    for (int off = 1; off < 64; off <<= 1) {
        s += __shfl_xor(s, off);
        sq += __shfl_xor(sq, off);
    }
    const float mu = s * 0.015625f;
    float var = sq * 0.015625f - mu * mu;
    var = fmaxf(var, 0.f);
    const float rstd = rsqrtf(var + 1e-5f);
    out[(r0 << 6) + lane] = (v - mu) * rstd * gamma[lane] + beta[lane];
}

extern "C" void kernel_launch(void* const* d_in, const int* in_sizes, int n_in,
                              void* d_out, int out_size, void* d_ws, size_t ws_size,
                              hipStream_t stream) {
    const float* x     = (const float*)d_in[0];
    const int*   graph = (const int*)d_in[1];
    const float* Wh    = (const float*)d_in[2];
    const float* bh    = (const float*)d_in[3];
    const float* Wo    = (const float*)d_in[4];
    const float* bo    = (const float*)d_in[5];
    const float* gamma = (const float*)d_in[6];
    const float* beta  = (const float*)d_in[7];
    float* out = (float*)d_out;

    // ---- workspace layout (16.5 MB, with reuse) ----
    char* ws = (char*)d_ws;
    unsigned int* mbitsT  = (unsigned int*)ws;                 // [0, 0.5M)
    unsigned short* h     = (unsigned short*)(ws + 0x080000);  // [0.5M, 8.5M)
    unsigned short* oh    = (unsigned short*)(ws + 0x880000);  // [8.5M, 16.5M)
    unsigned short* h2    = (unsigned short*)(ws + 0x080000);  // overlays h (dead after gat1)
    float2* ml            = (float2*)(ws + 0x280000);          // 512KB, in dead h region
    unsigned short* Opart = (unsigned short*)(ws + 0x880000);  // overlays oh (dead after mix)

    mask_kernel<<<16384, 256, 0, stream>>>(graph, mbitsT);
    proj_gemm<<<256, 256, 0, stream>>>(x, Wh, h);
    gat_flash<2, 0, 1><<<512, 256, 0, stream>>>(h, mbitsT, bh, 4, oh, nullptr);     // layer 1
    mix_gemm<<<256, 256, 0, stream>>>(oh, Wo, h2);
    gat_flash<2, 2, 4><<<512, 256, 0, stream>>>(h2, mbitsT, bo, 1, Opart, ml);      // layer 2 partials
    combine_ln<<<4096, 256, 0, stream>>>(Opart, ml, bo, gamma, beta, out);
}